// Round 13
// baseline (67616.827 us; speedup 1.0000x reference)
//
#include <hip/hip_runtime.h>
#include <cstdint>
#include <cstddef>

#define SEQ 128
#define BATCH 64
#define NVOCAB 10000
#define NREC 16
#define NWORK 240
#define NTOT 256

typedef __attribute__((ext_vector_type(8))) short short8;
typedef __attribute__((ext_vector_type(4))) float f32x4;

__device__ __forceinline__ unsigned short f2b(float f) {
  union { float f; unsigned u; } c; c.f = f;
  unsigned u = c.u;
  unsigned r = (u + 0x7fffu + ((u >> 16) & 1u)) >> 16;
  return (unsigned short)r;
}
__device__ __forceinline__ float b2f(unsigned u16) {
  union { unsigned u; float f; } c; c.u = u16 << 16; return c.f;
}
__device__ __forceinline__ float sigm(float x) { return 1.f / (1.f + __expf(-x)); }

__device__ __forceinline__ f32x4 mfma16(short8 a, short8 b, f32x4 c) {
  return __builtin_amdgcn_mfma_f32_16x16x32_bf16(a, b, c, 0, 0, 0);
}

// Coherent (cross-XCD) ops: bypass L1+L2, served at the coherence point.
__device__ __forceinline__ short8 ldg_coh(const unsigned short* p) {
  short8 r;
  asm volatile("global_load_dwordx4 %0, %1, off sc0 sc1" : "=v"(r) : "v"(p));
  return r;
}
__device__ __forceinline__ uint2 ldg_coh8(const unsigned short* p) {
  uint2 r;
  asm volatile("global_load_dwordx2 %0, %1, off sc0 sc1" : "=v"(r) : "v"(p));
  return r;
}
__device__ __forceinline__ void stg_coh8(unsigned short* p, uint2 v) {
  asm volatile("global_store_dwordx2 %0, %1, off sc0 sc1" :: "v"(p), "v"(v) : "memory");
}
__device__ __forceinline__ void st_stamp(int* p, int v) {
  asm volatile("global_store_dword %0, %1, off sc0 sc1" :: "v"(p), "v"(v) : "memory");
}
__device__ __forceinline__ int ld_stamp(const int* p) {
  int r;
  asm volatile("global_load_dword %0, %1, off sc0 sc1" : "=v"(r) : "v"(p));
  return r;
}

// Poll first 8 words of a stamp line (one word per producer WG). Per-wave.
template<int SLP>
__device__ __forceinline__ void wait8(const int* line, int need) {
  if (need < 0) return;
  int idx = threadIdx.x & 7;
  int guard = 0;
  for (;;) {
    int v = ld_stamp(line + idx);
    asm volatile("s_waitcnt vmcnt(0)" ::: "memory");
    if (__all(v >= need)) return;
    __builtin_amdgcn_s_sleep(SLP);
    if (++guard > 3000000) return;  // bail to wrong-output, never hang
  }
}
// Poll first 32 words (workers: 8 WGs x 4 waves).
template<int SLP>
__device__ __forceinline__ void wait32(const int* line, int need) {
  if (need < 0) return;
  int idx = threadIdx.x & 31;
  int guard = 0;
  for (;;) {
    int v = ld_stamp(line + idx);
    asm volatile("s_waitcnt vmcnt(0)" ::: "memory");
    if (__all(v >= need)) return;
    __builtin_amdgcn_s_sleep(SLP);
    if (++guard > 3000000) return;
  }
}

// ---------------- packing: src f32 (K x N row-major) -> frag-linear bf16 ----
// dst[nt][ks][lane][8]: value = src[row_off + ks*32 + (l>>4)*8 + j][nt*16 + (l&15)]
// This layout serves BOTH as B-frag of W and as A-frag of W^T.
__global__ void pack_frag(const float* __restrict__ src, unsigned short* __restrict__ dst,
                          int ksteps, int row_off, int src_ld, int ntiles, int nreal) {
  int tid = blockIdx.x * 256 + threadIdx.x;
  int total = ntiles * ksteps * 64;
  if (tid >= total) return;
  int l = tid & 63;
  int ks = (tid >> 6) % ksteps;
  int nt = tid / (64 * ksteps);
  int n = nt * 16 + (l & 15);
  bool valid = (n < nreal);
  int k0 = row_off + ks * 32 + ((l >> 4) << 3);
  short8 o;
  for (int j = 0; j < 8; ++j) {
    float x = valid ? src[(size_t)(k0 + j) * src_ld + n] : 0.f;
    o[j] = (short)f2b(x);
  }
  *reinterpret_cast<short8*>(&dst[(size_t)tid * 8]) = o;
}

// ------------- embedding gather into kmat layout [t][ktile][row][8] bf16 ----
__global__ void embed_gather(const int* __restrict__ inp, const float* __restrict__ tab,
                             unsigned short* __restrict__ XA) {
  int tid = blockIdx.x * 256 + threadIdx.x;
  if (tid >= SEQ * 64 * 64) return;
  int row = tid & 63;
  int kt = (tid >> 6) & 63;
  int t = tid >> 12;
  int v = inp[t * BATCH + row];
  const float* s = &tab[(size_t)v * 512 + kt * 8];
  const float scale = 22.627416997969522f; // sqrt(512)
  short8 o;
  for (int j = 0; j < 8; ++j) o[j] = (short)f2b(s[j] * scale);
  *reinterpret_cast<short8*>(&XA[(size_t)tid * 8]) = o;
}

// ------------- init: h0/h1 initial bf16 kmat buffers, stamps=-1 ----
__global__ void init_states(const float* __restrict__ hid, unsigned short* __restrict__ H0INITB,
                            unsigned short* __restrict__ H1INITB, int* __restrict__ stamps) {
  int idx = blockIdx.x * 256 + threadIdx.x;
  if (idx < 24 * 64) stamps[idx] = -1;
  if (idx >= 64 * 512) return;
  int row = idx >> 9, c = idx & 511;
  size_t ko = (((size_t)(c >> 3)) * 64 + row) * 8 + (c & 7);
  H0INITB[ko] = f2b(hid[idx]);
  H1INITB[ko] = f2b(hid[64 * 512 + idx]);
}

// ------------- generic 128x128 LDS-tiled bf16 GEMM, K=512 (prologue only) ----
// mode 0: C row-major [8192 x Nld]. mode 1: lane-aligned X-part layout:
//   C[(( (row>>6)*(Nld/4) + (col>>2) )*64 + (row&63))*4 + (col&3)]
__launch_bounds__(256, 2)
__global__ void gemm128(const unsigned short* __restrict__ A, const unsigned short* __restrict__ Bf,
                        const float* __restrict__ bias, float* __restrict__ C,
                        int Nld, int Nreal, int mode) {
  __shared__ __align__(16) unsigned short ldsA[16 * 512];
  __shared__ __align__(16) unsigned short ldsB[16 * 512];
  int nb = blockIdx.x, yb = blockIdx.y;
  int l = threadIdx.x & 63, w = threadIdx.x >> 6;
  int mh = w >> 1, nh = w & 1;
  f32x4 acc[4][4] = {};
  for (int ko = 0; ko < 8; ++ko) {
    __syncthreads();
    for (int j = 0; j < 4; ++j) {
      int c = w * 4 + j;
      int m8 = c >> 1, ks = c & 1;
      int t = yb * 2 + (m8 >> 2);
      int kt = ko * 8 + ks * 4 + (l >> 4);
      int row = (m8 & 3) * 16 + (l & 15);
      size_t gidx = (((size_t)t * 64 + kt) * 64 + row) * 8;
      *reinterpret_cast<short8*>(&ldsA[(size_t)c * 512 + l * 8]) =
          *reinterpret_cast<const short8*>(&A[gidx]);
      size_t gb = (((size_t)(nb * 8 + (c >> 1)) * 16) + (size_t)(ko * 2 + (c & 1))) * 512 + (size_t)l * 8;
      *reinterpret_cast<short8*>(&ldsB[(size_t)c * 512 + l * 8]) =
          *reinterpret_cast<const short8*>(&Bf[gb]);
    }
    __syncthreads();
    for (int ks = 0; ks < 2; ++ks) {
      short8 a[4], b[4];
      for (int mt = 0; mt < 4; ++mt) {
        int m8 = mh * 4 + mt;
        a[mt] = *reinterpret_cast<const short8*>(&ldsA[((size_t)(m8 * 2 + ks) * 64 + l) * 8]);
      }
      for (int nt = 0; nt < 4; ++nt) {
        int n8 = nh * 4 + nt;
        b[nt] = *reinterpret_cast<const short8*>(&ldsB[((size_t)(n8 * 2 + ks) * 64 + l) * 8]);
      }
      for (int mt = 0; mt < 4; ++mt)
        for (int nt = 0; nt < 4; ++nt)
          acc[mt][nt] = mfma16(a[mt], b[nt], acc[mt][nt]);
    }
  }
  for (int mt = 0; mt < 4; ++mt) {
    for (int nt = 0; nt < 4; ++nt) {
      int col = nb * 128 + nh * 64 + nt * 16 + (l & 15);
      if (col >= Nreal) continue;
      float bv = bias[col];
      int row0 = yb * 128 + mh * 64 + mt * 16 + ((l >> 4) << 2);
      for (int r = 0; r < 4; ++r) {
        float v = acc[mt][nt][r] + bv;
        int row = row0 + r;
        if (mode) {
          size_t idx = (((size_t)(row >> 6) * (Nld >> 2) + (col >> 2)) * 64 + (row & 63)) * 4 + (col & 3);
          C[idx] = v;
        } else {
          C[(size_t)row * Nld + col] = v;
        }
      }
    }
  }
}

// ------------- recurrence: ONE exchange per step (redundant full-r) ----
// 16 rec WGs: 8 per layer, each owns 64 output cols [64g, 64g+64).
// Waves are M-split (wave w = batch rows [16w,16w+16)); every wave computes
// the FULL r-gate (all 512 cols) redundantly so r*h is local -> no rh exchange.
// All matmuls transposed: mfma(A=W^T frag (= existing pack), B=h^T frag
// (= existing kmat load)); output lands (col=batch=s, row=outcol=q*4+j) so
// u/r/cell/hf are lane-aligned and the epilogue is in-register. No
// __syncthreads in the loop; per-wave stamps.
// Stamp lines (64 ints): 0-7 SH0[w][rep] (words=producer g), 8-15 SH1[w][rep],
// 16-23 SHW replicas (words = g*4+w).
template<int LAYER>
__device__ void rec_layer(
    int g, const unsigned short* __restrict__ Wg, const unsigned short* __restrict__ Wc,
    const float* __restrict__ XgR, const float* __restrict__ XcR,
    const float* __restrict__ bg1, const float* __restrict__ bc1,
    const float* __restrict__ hidden,
    unsigned short* __restrict__ H0ALL, unsigned short* __restrict__ H1ALL,
    const unsigned short* __restrict__ H0INITB, const unsigned short* __restrict__ H1INITB,
    int* __restrict__ stamps, float* __restrict__ hidden_out, char* smem) {
  constexpr int KS = LAYER ? 32 : 16;   // gate/cell K-steps
  const int tid = threadIdx.x;
  const int l = tid & 63, w = tid >> 6;
  const int s = l & 15, q = l >> 4;
  const int batch = 16 * w + s;
  unsigned short* rhL = (unsigned short*)smem + (size_t)w * 8192;  // 16KB/wave

  const int rep = g & 1;
  int* SH0r = stamps + (w * 2 + rep) * 64;
  int* SH1r = stamps + (8 + w * 2 + rep) * 64;
  int* SWa  = stamps + ((LAYER ? 8 : 0) + w * 2 + 0) * 64;
  int* SWb  = stamps + ((LAYER ? 8 : 0) + w * 2 + 1) * 64;

  // f32 h master in registers: hf[ct][j] = h[batch][64g + ct*16 + q*4 + j]
  f32x4 hf[4];
#pragma unroll
  for (int ct = 0; ct < 4; ++ct)
    hf[ct] = *reinterpret_cast<const f32x4*>(
        &hidden[(size_t)LAYER * 32768 + (size_t)batch * 512 + 64 * g + ct * 16 + q * 4]);

  for (int t = 0; t < 128; ++t) {
    const unsigned short* B0;
    const unsigned short* B1 = nullptr;
    if constexpr (LAYER) {
      B0 = H0ALL + (size_t)t * 32768;
      B1 = t ? (H1ALL + (size_t)(t - 1) * 32768) : H1INITB;
    } else {
      B0 = t ? (H0ALL + (size_t)(t - 1) * 32768) : H0INITB;
    }

    // ---- wait + load h fragments (B-operand of transposed matmuls) ----
    if constexpr (LAYER == 0) {
      wait8<1>(SH0r, t - 1);
    } else {
      wait8<1>(SH0r, t);
      wait8<1>(SH1r, t - 1);
    }
    short8 bh0[16], bh1[LAYER ? 16 : 1];
#pragma unroll
    for (int ks = 0; ks < 16; ++ks)
      bh0[ks] = ldg_coh(&B0[(((size_t)(ks * 4 + q)) * 64 + batch) * 8]);
    if constexpr (LAYER) {
#pragma unroll
      for (int ks = 0; ks < 16; ++ks)
        bh1[ks] = ldg_coh(&B1[(((size_t)(ks * 4 + q)) * 64 + batch) * 8]);
    }
    asm volatile("s_waitcnt vmcnt(0)" ::: "memory");
    __builtin_amdgcn_sched_barrier(0);

    // ---- u-gate (my 64 cols): 4 ct accumulators, ks-outer for ILP ----
    f32x4 accu[4] = {};
#pragma unroll
    for (int ks = 0; ks < KS; ++ks) {
      short8 b = (LAYER && ks >= 16) ? bh1[ks - 16] : bh0[ks & 15];
#pragma unroll
      for (int ct = 0; ct < 4; ++ct) {
        short8 aw = *reinterpret_cast<const short8*>(
            &Wg[(((size_t)(4 * g + ct) * KS + ks) * 64 + l) * 8]);
        accu[ct] = mfma16(aw, b, accu[ct]);
      }
    }
    f32x4 u_[4];
#pragma unroll
    for (int ct = 0; ct < 4; ++ct) {
      f32x4 xu;
      if constexpr (LAYER == 0)
        xu = *reinterpret_cast<const f32x4*>(
            &XgR[(((size_t)t * 256 + 16 * g + ct * 4 + q) * 64 + batch) * 4]);
      else
        xu = *reinterpret_cast<const f32x4*>(&bg1[64 * g + ct * 16 + q * 4]);
#pragma unroll
      for (int j = 0; j < 4; ++j) u_[ct][j] = sigm(accu[ct][j] + xu[j]);
    }

    // ---- full r-gate (all 512 cols, redundant) in 2 half-passes ----
    const unsigned short* hsrc = LAYER ? B1 : B0;
#pragma unroll
    for (int half = 0; half < 2; ++half) {
      uint2 hv[16];
#pragma unroll
      for (int r2 = 0; r2 < 16; ++r2) {
        int rt = half * 16 + r2;
        hv[r2] = ldg_coh8(&hsrc[((size_t)(rt * 2 + (q >> 1)) * 64 + batch) * 8 + (q & 1) * 4]);
      }
      f32x4 accr[16] = {};
#pragma unroll
      for (int ks = 0; ks < KS; ++ks) {
        short8 b = (LAYER && ks >= 16) ? bh1[ks - 16] : bh0[ks & 15];
#pragma unroll
        for (int r2 = 0; r2 < 16; ++r2) {
          int nt = 32 + half * 16 + r2;
          short8 aw = *reinterpret_cast<const short8*>(
              &Wg[(((size_t)nt * KS + ks) * 64 + l) * 8]);
          accr[r2] = mfma16(aw, b, accr[r2]);
        }
      }
      asm volatile("s_waitcnt vmcnt(0)" ::: "memory");  // hv ready
      __builtin_amdgcn_sched_barrier(0);
#pragma unroll
      for (int r2 = 0; r2 < 16; ++r2) {
        int rt = half * 16 + r2;
        f32x4 xr;
        if constexpr (LAYER == 0)
          xr = *reinterpret_cast<const f32x4*>(
              &XgR[(((size_t)t * 256 + 128 + rt * 4 + q) * 64 + batch) * 4]);
        else
          xr = *reinterpret_cast<const f32x4*>(&bg1[512 + rt * 16 + q * 4]);
        float v0 = sigm(accr[r2][0] + xr[0]) * b2f(hv[r2].x & 0xffffu);
        float v1 = sigm(accr[r2][1] + xr[1]) * b2f(hv[r2].x >> 16);
        float v2 = sigm(accr[r2][2] + xr[2]) * b2f(hv[r2].y & 0xffffu);
        float v3 = sigm(accr[r2][3] + xr[3]) * b2f(hv[r2].y >> 16);
        uint2 pk;
        pk.x = (unsigned)f2b(v0) | ((unsigned)f2b(v1) << 16);
        pk.y = (unsigned)f2b(v2) | ((unsigned)f2b(v3) << 16);
        *reinterpret_cast<uint2*>(&rhL[((size_t)(rt * 2 + (q >> 1)) * 16 + s) * 8 + (q & 1) * 4]) = pk;
      }
    }

    // ---- cell (my 64 cols): K = [h0 | rh] for L1, [rh] for L0 ----
    f32x4 accc[4] = {};
#pragma unroll
    for (int ks = 0; ks < KS; ++ks) {
      short8 b;
      if (LAYER && ks < 16) {
        b = bh0[ks];
      } else {
        int kc = LAYER ? (ks - 16) : ks;
        b = *reinterpret_cast<const short8*>(&rhL[((size_t)(kc * 4 + q) * 16 + s) * 8]);
      }
#pragma unroll
      for (int ct = 0; ct < 4; ++ct) {
        short8 aw = *reinterpret_cast<const short8*>(
            &Wc[(((size_t)(4 * g + ct) * KS + ks) * 64 + l) * 8]);
        accc[ct] = mfma16(aw, b, accc[ct]);
      }
    }

    // ---- epilogue: h' in-register, 8B coherent stores to ring ----
    unsigned short* Hdst = (LAYER ? H1ALL : H0ALL) + (size_t)t * 32768;
#pragma unroll
    for (int ct = 0; ct < 4; ++ct) {
      f32x4 xc;
      if constexpr (LAYER == 0)
        xc = *reinterpret_cast<const f32x4*>(
            &XcR[(((size_t)t * 128 + 16 * g + ct * 4 + q) * 64 + batch) * 4]);
      else
        xc = *reinterpret_cast<const f32x4*>(&bc1[64 * g + ct * 16 + q * 4]);
      float hn[4];
#pragma unroll
      for (int j = 0; j < 4; ++j) {
        float cv = tanhf(accc[ct][j] + xc[j]);
        hn[j] = hf[ct][j] + u_[ct][j] * (cv - hf[ct][j]);
        hf[ct][j] = hn[j];
      }
      uint2 pk;
      pk.x = (unsigned)f2b(hn[0]) | ((unsigned)f2b(hn[1]) << 16);
      pk.y = (unsigned)f2b(hn[2]) | ((unsigned)f2b(hn[3]) << 16);
      stg_coh8(&Hdst[((size_t)(8 * g + 2 * ct + (q >> 1)) * 64 + batch) * 8 + (q & 1) * 4], pk);
    }
    asm volatile("s_waitcnt vmcnt(0)" ::: "memory");
    if (l == 0) {
      st_stamp(&SWa[g], t);
      st_stamp(&SWb[g], t);
      if constexpr (LAYER) {
#pragma unroll
        for (int r8 = 0; r8 < 8; ++r8) st_stamp(&stamps[(16 + r8) * 64 + g * 4 + w], t);
      }
    }
  }

  // ---- final hidden (f32) from registers ----
#pragma unroll
  for (int ct = 0; ct < 4; ++ct)
    *reinterpret_cast<f32x4*>(
        &hidden_out[(size_t)LAYER * 32768 + (size_t)batch * 512 + 64 * g + ct * 16 + q * 4]) = hf[ct];
}

// ------------- worker path: logits tiles, nb-major (L2-resident B-block) ----
__device__ void worker_path(int wid, const unsigned short* __restrict__ A,
                            const unsigned short* __restrict__ Bf,
                            const float* __restrict__ bias, float* __restrict__ C,
                            const int* __restrict__ stamps, char* smem) {
  unsigned short* ldsA = (unsigned short*)smem;
  unsigned short* ldsB = (unsigned short*)(smem + 16384);
  const int* rep = stamps + (16 + (wid & 7)) * 64;
  int l = threadIdx.x & 63, w = threadIdx.x >> 6;
  int mh = w >> 1, nh = w & 1;
  int nb = wid % 80;
  int helper = wid / 80;       // 0..2, exactly 3 helpers per nb
  for (int tp = helper; tp < 64; tp += 3) {
    wait32<16>(rep, 2 * tp + 1);
    f32x4 acc[4][4] = {};
    for (int ko = 0; ko < 8; ++ko) {
      __syncthreads();
      for (int j = 0; j < 4; ++j) {
        int c = w * 4 + j;
        int m8 = c >> 1, ks = c & 1;
        int t = tp * 2 + (m8 >> 2);
        int kt = ko * 8 + ks * 4 + (l >> 4);
        int row = (m8 & 3) * 16 + (l & 15);
        size_t gidx = (((size_t)t * 64 + kt) * 64 + row) * 8;
        *reinterpret_cast<short8*>(&ldsA[(size_t)c * 512 + l * 8]) =
            *reinterpret_cast<const short8*>(&A[gidx]);
        size_t gb = (((size_t)(nb * 8 + (c >> 1)) * 16) + (size_t)(ko * 2 + (c & 1))) * 512 + (size_t)l * 8;
        *reinterpret_cast<short8*>(&ldsB[(size_t)c * 512 + l * 8]) =
            *reinterpret_cast<const short8*>(&Bf[gb]);
      }
      __syncthreads();
      for (int ks = 0; ks < 2; ++ks) {
        short8 a[4], b[4];
        for (int mt = 0; mt < 4; ++mt)
          a[mt] = *reinterpret_cast<const short8*>(&ldsA[((size_t)((mh * 4 + mt) * 2 + ks) * 64 + l) * 8]);
        for (int nt = 0; nt < 4; ++nt)
          b[nt] = *reinterpret_cast<const short8*>(&ldsB[((size_t)((nh * 4 + nt) * 2 + ks) * 64 + l) * 8]);
        for (int mt = 0; mt < 4; ++mt)
          for (int nt = 0; nt < 4; ++nt)
            acc[mt][nt] = mfma16(a[mt], b[nt], acc[mt][nt]);
      }
    }
    for (int mt = 0; mt < 4; ++mt) {
      for (int nt = 0; nt < 4; ++nt) {
        int col = nb * 128 + nh * 64 + nt * 16 + (l & 15);
        if (col >= NVOCAB) continue;
        float bv = bias[col];
        int row0 = tp * 128 + mh * 64 + mt * 16 + ((l >> 4) << 2);
        for (int r = 0; r < 4; ++r)
          C[(size_t)(row0 + r) * NVOCAB + col] = acc[mt][nt][r] + bv;
      }
    }
  }
}

__launch_bounds__(256, 1)
__global__ void fused_persist(const unsigned short* __restrict__ Wg0h, const unsigned short* __restrict__ Wc0h,
                              const unsigned short* __restrict__ Wg1, const unsigned short* __restrict__ Wc1,
                              const float* __restrict__ XgR, const float* __restrict__ XcR,
                              const float* __restrict__ bg1, const float* __restrict__ bc1,
                              const float* __restrict__ hidden,
                              unsigned short* __restrict__ H0ALL, unsigned short* __restrict__ H1ALL,
                              const unsigned short* __restrict__ H0INITB, const unsigned short* __restrict__ H1INITB,
                              int* __restrict__ stamps, float* __restrict__ hidden_out,
                              const unsigned short* __restrict__ Wout_f, const float* __restrict__ bout,
                              float* __restrict__ out) {
  extern __shared__ __align__(16) char smem[];
  int wg = blockIdx.x;
  if (wg >= NREC) {
    worker_path(wg - NREC, H1ALL, Wout_f, bout, out, stamps, smem);
    return;
  }
  if (wg < 8)
    rec_layer<0>(wg, Wg0h, Wc0h, XgR, XcR, bg1, bc1, hidden, H0ALL, H1ALL,
                 H0INITB, H1INITB, stamps, hidden_out, smem);
  else
    rec_layer<1>(wg - 8, Wg1, Wc1, XgR, XcR, bg1, bc1, hidden, H0ALL, H1ALL,
                 H0INITB, H1INITB, stamps, hidden_out, smem);
}

static inline int gridFor(long long n) { return (int)((n + 255) / 256); }

extern "C" void kernel_launch(void* const* d_in, const int* in_sizes, int n_in,
                              void* d_out, int out_size, void* d_ws, size_t ws_size,
                              hipStream_t stream) {
  const int*   inputs = (const int*)d_in[0];
  const float* hidden = (const float*)d_in[1];
  const float* embtab = (const float*)d_in[2];
  const float* Wg0 = (const float*)d_in[3];
  const float* bg0 = (const float*)d_in[4];
  const float* Wc0 = (const float*)d_in[5];
  const float* bc0 = (const float*)d_in[6];
  const float* Wg1 = (const float*)d_in[7];
  const float* bg1 = (const float*)d_in[8];
  const float* Wc1 = (const float*)d_in[9];
  const float* bc1 = (const float*)d_in[10];
  const float* Wout = (const float*)d_in[11];
  const float* bout = (const float*)d_in[12];
  float* out = (float*)d_out;

  // ---- workspace carve ----
  char* p = (char*)d_ws;
  size_t off = 0;
  auto carve = [&](size_t bytes) { char* r = p + off; off += (bytes + 255) & ~(size_t)255; return (void*)r; };
  unsigned short* XA     = (unsigned short*)carve((size_t)8192 * 512 * 2);
  unsigned short* Wg0x_f = (unsigned short*)carve((size_t)512 * 1024 * 2);
  unsigned short* Wg0h_f = (unsigned short*)carve((size_t)512 * 1024 * 2);
  unsigned short* Wc0x_f = (unsigned short*)carve((size_t)512 * 512 * 2);
  unsigned short* Wc0h_f = (unsigned short*)carve((size_t)512 * 512 * 2);
  unsigned short* Wg1_f  = (unsigned short*)carve((size_t)1024 * 1024 * 2);
  unsigned short* Wc1_f  = (unsigned short*)carve((size_t)1024 * 512 * 2);
  unsigned short* Wout_f = (unsigned short*)carve((size_t)512 * 10240 * 2);
  float* XgR = (float*)carve((size_t)8192 * 1024 * 4);
  float* XcR = (float*)carve((size_t)8192 * 512 * 4);
  unsigned short* H1ALL  = (unsigned short*)carve((size_t)128 * 32768 * 2);
  unsigned short* H0ALL  = (unsigned short*)carve((size_t)128 * 32768 * 2);
  unsigned short* H0INITB= (unsigned short*)carve((size_t)32768 * 2);
  unsigned short* H1INITB= (unsigned short*)carve((size_t)32768 * 2);
  int* stamps = (int*)carve(24 * 64 * 4);
  if (off > ws_size) return;

  // ---- pack weights into frag-linear bf16 ----
  pack_frag<<<gridFor(64LL * 16 * 64), 256, 0, stream>>>(Wg0, Wg0x_f, 16, 0,   1024, 64, 1024);
  pack_frag<<<gridFor(64LL * 16 * 64), 256, 0, stream>>>(Wg0, Wg0h_f, 16, 512, 1024, 64, 1024);
  pack_frag<<<gridFor(32LL * 16 * 64), 256, 0, stream>>>(Wc0, Wc0x_f, 16, 0,   512,  32, 512);
  pack_frag<<<gridFor(32LL * 16 * 64), 256, 0, stream>>>(Wc0, Wc0h_f, 16, 512, 512,  32, 512);
  pack_frag<<<gridFor(64LL * 32 * 64), 256, 0, stream>>>(Wg1, Wg1_f,  32, 0,   1024, 64, 1024);
  pack_frag<<<gridFor(32LL * 32 * 64), 256, 0, stream>>>(Wc1, Wc1_f,  32, 0,   512,  32, 512);
  pack_frag<<<gridFor(640LL * 16 * 64), 256, 0, stream>>>(Wout, Wout_f, 16, 0, 10000, 640, 10000);

  // ---- embedding + state/stamp init ----
  embed_gather<<<gridFor((long long)SEQ * 64 * 64), 256, 0, stream>>>(inputs, embtab, XA);
  init_states<<<gridFor(32768), 256, 0, stream>>>(hidden, H0INITB, H1INITB, stamps);

  // ---- precompute x-parts of layer-0 gates/cell in lane-aligned layout ----
  gemm128<<<dim3(8, 64), 256, 0, stream>>>(XA, Wg0x_f, bg0, XgR, 1024, 1024, 1);
  gemm128<<<dim3(4, 64), 256, 0, stream>>>(XA, Wc0x_f, bc0, XcR, 512, 512, 1);

  // ---- fused persistent: 16 rec WGs (one-hop recurrence) + 240 workers ----
  // 81920B dynamic LDS -> 1 WG/CU.
  fused_persist<<<NTOT, 256, 81920, stream>>>(Wg0h_f, Wc0h_f, Wg1_f, Wc1_f, XgR, XcR,
                                              bg1, bc1, hidden, H0ALL, H1ALL,
                                              H0INITB, H1INITB, stamps,
                                              out + (size_t)81920000,
                                              Wout_f, bout, out);
}

// Round 14
// 1281.200 us; speedup vs baseline: 52.7762x; 52.7762x over previous
//
#include <hip/hip_runtime.h>
#include <cstdint>
#include <cstddef>

#define SEQ 128
#define BATCH 64
#define NVOCAB 10000
#define NREC 64
#define NWORK 192
#define NTOT 256

typedef __attribute__((ext_vector_type(8))) short short8;
typedef __attribute__((ext_vector_type(4))) float f32x4;

__device__ __forceinline__ unsigned short f2b(float f) {
  union { float f; unsigned u; } c; c.f = f;
  unsigned u = c.u;
  unsigned r = (u + 0x7fffu + ((u >> 16) & 1u)) >> 16;
  return (unsigned short)r;
}

__device__ __forceinline__ f32x4 mfma16(short8 a, short8 b, f32x4 c) {
  return __builtin_amdgcn_mfma_f32_16x16x32_bf16(a, b, c, 0, 0, 0);
}

// Coherent (cross-XCD) ops: bypass L1+L2, served at the coherence point.
__device__ __forceinline__ short8 ldg_coh(const unsigned short* p) {
  short8 r;
  asm volatile("global_load_dwordx4 %0, %1, off sc0 sc1" : "=v"(r) : "v"(p));
  return r;
}
__device__ __forceinline__ void stg_coh(unsigned short* p, short8 v) {
  asm volatile("global_store_dwordx4 %0, %1, off sc0 sc1" :: "v"(p), "v"(v) : "memory");
}
__device__ __forceinline__ void st_stamp(int* p, int v) {
  asm volatile("global_store_dword %0, %1, off sc0 sc1" :: "v"(p), "v"(v) : "memory");
}
__device__ __forceinline__ int ld_stamp(const int* p) {
  int r;
  asm volatile("global_load_dword %0, %1, off sc0 sc1" : "=v"(r) : "v"(p));
  return r;
}

// Wait on a NW-word subset [base, base+NW) of a stamp line (NW power of 2,
// <= 64). Stamp words are per (producer WG, half): word = 2*g + kg.
template<int SLP, int NW>
__device__ __forceinline__ void wait_sub(const int* rep, int base, int need) {
  if (need < 0) return;
  int idx = base + (threadIdx.x & (NW - 1));
  int guard = 0;
  for (;;) {
    int v = ld_stamp(rep + idx);
    asm volatile("s_waitcnt vmcnt(0)" ::: "memory");
    if (__all(v >= need)) return;
    __builtin_amdgcn_s_sleep(SLP);
    if (++guard > 3000000) return;  // bail to wrong-output, never hang
  }
}

// ---------------- packing: src f32 (K x N row-major) -> frag-linear bf16 ----
__global__ void pack_frag(const float* __restrict__ src, unsigned short* __restrict__ dst,
                          int ksteps, int row_off, int src_ld, int ntiles, int mode, int nreal) {
  int tid = blockIdx.x * 256 + threadIdx.x;
  int total = ntiles * ksteps * 64;
  if (tid >= total) return;
  int l = tid & 63;
  int ks = (tid >> 6) % ksteps;
  int nt = tid / (64 * ksteps);
  int n = nt * 16 + (l & 15);
  int col;
  bool valid = true;
  if (mode == 1) {
    int jc = n >> 5, s = n & 31;
    col = (s < 16) ? (16 * jc + s) : (512 + 16 * jc + (s - 16));
  } else {
    col = n;
    valid = (n < nreal);
  }
  int k0 = row_off + ks * 32 + ((l >> 4) << 3);
  short8 o;
  for (int j = 0; j < 8; ++j) {
    float x = valid ? src[(size_t)(k0 + j) * src_ld + col] : 0.f;
    o[j] = (short)f2b(x);
  }
  *reinterpret_cast<short8*>(&dst[(size_t)tid * 8]) = o;
}

__global__ void pack_bias(const float* __restrict__ bg0, const float* __restrict__ bg1,
                          float* __restrict__ bg0p, float* __restrict__ bg1p) {
  int p = blockIdx.x * 256 + threadIdx.x;
  if (p >= 1024) return;
  int jc = p >> 5, s = p & 31;
  int col = (s < 16) ? (16 * jc + s) : (512 + 16 * jc + (s - 16));
  bg0p[p] = bg0[col];
  bg1p[p] = bg1[col];
}

// ------------- embedding gather into kmat layout [t][ktile][row][8] bf16 ----
__global__ void embed_gather(const int* __restrict__ inp, const float* __restrict__ tab,
                             unsigned short* __restrict__ XA) {
  int tid = blockIdx.x * 256 + threadIdx.x;
  if (tid >= SEQ * 64 * 64) return;
  int row = tid & 63;
  int kt = (tid >> 6) & 63;
  int t = tid >> 12;
  int v = inp[t * BATCH + row];
  const float* s = &tab[(size_t)v * 512 + kt * 8];
  const float scale = 22.627416997969522f; // sqrt(512)
  short8 o;
  for (int j = 0; j < 8; ++j) o[j] = (short)f2b(s[j] * scale);
  *reinterpret_cast<short8*>(&XA[(size_t)tid * 8]) = o;
}

// ------------- init: h0/h1 initial bf16 kmat buffers, stamps=-1 ----
__global__ void init_states(const float* __restrict__ hid, unsigned short* __restrict__ H0INITB,
                            unsigned short* __restrict__ H1INITB, int* __restrict__ stamps) {
  int idx = blockIdx.x * 256 + threadIdx.x;
  if (idx < 24 * 64) stamps[idx] = -1;
  if (idx >= 64 * 512) return;
  int row = idx >> 9, c = idx & 511;
  size_t ko = (((size_t)(c >> 3)) * 64 + row) * 8 + (c & 7);
  H0INITB[ko] = f2b(hid[idx]);
  H1INITB[ko] = f2b(hid[64 * 512 + idx]);
}

// ------------- generic 128x128 LDS-tiled bf16 GEMM, K=512 (prologue only) ----
__launch_bounds__(256, 2)
__global__ void gemm128(const unsigned short* __restrict__ A, const unsigned short* __restrict__ Bf,
                        const float* __restrict__ bias, float* __restrict__ C,
                        int Nld, int Nreal) {
  __shared__ __align__(16) unsigned short ldsA[16 * 512];
  __shared__ __align__(16) unsigned short ldsB[16 * 512];
  int nb = blockIdx.x, yb = blockIdx.y;
  int l = threadIdx.x & 63, w = threadIdx.x >> 6;
  int mh = w >> 1, nh = w & 1;
  f32x4 acc[4][4] = {};
  for (int ko = 0; ko < 8; ++ko) {
    __syncthreads();
    for (int j = 0; j < 4; ++j) {
      int c = w * 4 + j;
      int m8 = c >> 1, ks = c & 1;
      int t = yb * 2 + (m8 >> 2);
      int kt = ko * 8 + ks * 4 + (l >> 4);
      int row = (m8 & 3) * 16 + (l & 15);
      size_t gidx = (((size_t)t * 64 + kt) * 64 + row) * 8;
      *reinterpret_cast<short8*>(&ldsA[(size_t)c * 512 + l * 8]) =
          *reinterpret_cast<const short8*>(&A[gidx]);
      size_t gb = (((size_t)(nb * 8 + (c >> 1)) * 16) + (size_t)(ko * 2 + (c & 1))) * 512 + (size_t)l * 8;
      *reinterpret_cast<short8*>(&ldsB[(size_t)c * 512 + l * 8]) =
          *reinterpret_cast<const short8*>(&Bf[gb]);
    }
    __syncthreads();
    for (int ks = 0; ks < 2; ++ks) {
      short8 a[4], b[4];
      for (int mt = 0; mt < 4; ++mt) {
        int m8 = mh * 4 + mt;
        a[mt] = *reinterpret_cast<const short8*>(&ldsA[((size_t)(m8 * 2 + ks) * 64 + l) * 8]);
      }
      for (int nt = 0; nt < 4; ++nt) {
        int n8 = nh * 4 + nt;
        b[nt] = *reinterpret_cast<const short8*>(&ldsB[((size_t)(n8 * 2 + ks) * 64 + l) * 8]);
      }
      for (int mt = 0; mt < 4; ++mt)
        for (int nt = 0; nt < 4; ++nt)
          acc[mt][nt] = mfma16(a[mt], b[nt], acc[mt][nt]);
    }
  }
  for (int mt = 0; mt < 4; ++mt) {
    for (int nt = 0; nt < 4; ++nt) {
      int col = nb * 128 + nh * 64 + nt * 16 + (l & 15);
      if (col >= Nreal) continue;
      float bv = bias[col];
      int row0 = yb * 128 + mh * 64 + mt * 16 + ((l >> 4) << 2);
      for (int r = 0; r < 4; ++r)
        C[(size_t)(row0 + r) * Nld + col] = acc[mt][nt][r] + bv;
    }
  }
}

// ------------- recurrence layer (stamp-synced, per-HALF early stamps) ----
// Stamp lines (64 ints): 0-3 SR0, 4-7 SR1, 8-11 SH0, 12-15 SH1, 16-23 SHW.
// Word within line = 2*g + kg (kg = which half/wave wrote the data). Lane 0
// of waves 0,1 stamp their own word right after their store-drain, BEFORE the
// end-of-phase barrier -- stamps leave ~a barrier earlier than R10. Safety:
// the pre-epilogue __syncthreads still forces the union of all 4 waves' waits
// (all 64 words >= t) before any buffer overwrite, same argument as R10.
template<int KS, int LAYER>
__device__ void rec_layer(
    int g, const unsigned short* __restrict__ Wg, const unsigned short* __restrict__ Wc,
    const float* __restrict__ Xg0p, const float* __restrict__ Xc0p,
    const float* __restrict__ bg1p, const float* __restrict__ bc1,
    const float* __restrict__ hidden,
    unsigned short* __restrict__ H0ALL, unsigned short* __restrict__ H1ALL,
    const unsigned short* __restrict__ H0INITB, const unsigned short* __restrict__ H1INITB,
    unsigned short* __restrict__ RH0, unsigned short* __restrict__ RH1,
    int* __restrict__ stamps, float* __restrict__ hidden_out,
    float (&red)[4][64][33], float (&u_lds)[64][17], float (&hf)[64][17]) {
  constexpr int KQ = KS / 4;
  const int tid = threadIdx.x;
  const int l = tid & 63, w = tid >> 6;
  const int s = l & 15, q = l >> 4;

  int* SR   = stamps + (LAYER ? 4 : 0) * 64;
  int* SH0  = stamps + 8 * 64;
  int* SH1  = stamps + 12 * 64;
  int* SHW  = stamps + 16 * 64;
  int* mySH = LAYER ? SH1 : SH0;
  const int repw = ((g + w) & 3) * 64;
  unsigned short* myRH = LAYER ? RH1 : RH0;

  // ---- weights to registers (once, cached) ----
  short8 bg[2][KQ];
  short8 bc[KQ];
#pragma unroll
  for (int kk = 0; kk < KQ; ++kk) {
    int ks = w * KQ + kk;
    bg[0][kk] = *reinterpret_cast<const short8*>(&Wg[(((size_t)(2 * g) * KS + ks) * 64 + l) * 8]);
    bg[1][kk] = *reinterpret_cast<const short8*>(&Wg[(((size_t)(2 * g + 1) * KS + ks) * 64 + l) * 8]);
    bc[kk]    = *reinterpret_cast<const short8*>(&Wc[(((size_t)g * KS + ks) * 64 + l) * 8]);
  }

  // ---- init f32 h slice in LDS ----
  {
    int col = tid & 15;
#pragma unroll
    for (int rr = 0; rr < 4; ++rr) {
      int row = (tid >> 4) * 4 + rr;
      hf[row][col] = hidden[(size_t)LAYER * 32768 + (size_t)row * 512 + 16 * g + col];
    }
  }
  __syncthreads();

  for (int t = 0; t < 128; ++t) {
    // ---- L0: prefetch this step's X-part adds (no stamp dependency) ----
    float xg[8], xc[8];
    if constexpr (LAYER == 0) {
      int row = tid & 63;
      int kg = (tid >> 6) & 1;
      int base = (tid < 128) ? 16 : 0;
#pragma unroll
      for (int j = 0; j < 8; ++j)
        xg[j] = Xg0p[((size_t)(t * 64 + row)) * 1024 + g * 32 + base + kg * 8 + j];
#pragma unroll
      for (int j = 0; j < 8; ++j)
        xc[j] = Xc0p[((size_t)(t * 64 + row)) * 512 + 16 * g + kg * 8 + j];
    }

    const unsigned short* A0 = LAYER ? (H0ALL + (size_t)t * 32768)
                                     : (t ? (H0ALL + (size_t)(t - 1) * 32768) : H0INITB);
    const unsigned short* A1 = nullptr;
    if (LAYER) A1 = t ? (H1ALL + (size_t)(t - 1) * 32768) : H1INITB;

    // ============ phase A: gates ============
    {
      f32x4 acc[4][2] = {};
      if constexpr (LAYER == 0) {
        wait_sub<1, 16>(SH0 + repw, 16 * w, t - 1);
        short8 a[4][4];
#pragma unroll
        for (int kk2 = 0; kk2 < 4; ++kk2) {
          int kl = w * 4 + kk2;
#pragma unroll
          for (int mt = 0; mt < 4; ++mt)
            a[kk2][mt] = ldg_coh(&A0[(((size_t)(kl * 4 + q)) * 64 + mt * 16 + s) * 8]);
        }
        asm volatile("s_waitcnt vmcnt(0)" ::: "memory");
        __builtin_amdgcn_sched_barrier(0);
#pragma unroll
        for (int kk2 = 0; kk2 < 4; ++kk2)
#pragma unroll
          for (int mt = 0; mt < 4; ++mt) {
            acc[mt][0] = mfma16(a[kk2][mt], bg[0][kk2], acc[mt][0]);
            acc[mt][1] = mfma16(a[kk2][mt], bg[1][kk2], acc[mt][1]);
          }
      } else {
        // per-wave dependency wait (32-word half-ranges)
        if (w >= 2) wait_sub<1, 32>(SH1 + repw, 32 * (w & 1), t - 1);
        else        wait_sub<1, 32>(SH0 + repw, 32 * (w & 1), t);
        const unsigned short* ab = (w >= 2) ? A1 : A0;
#pragma unroll
        for (int hb = 0; hb < 2; ++hb) {
          short8 a[4][4];
#pragma unroll
          for (int kk2 = 0; kk2 < 4; ++kk2) {
            int kl = ((w & 1) * 8 + hb * 4 + kk2);
#pragma unroll
            for (int mt = 0; mt < 4; ++mt)
              a[kk2][mt] = ldg_coh(&ab[(((size_t)(kl * 4 + q)) * 64 + mt * 16 + s) * 8]);
          }
          asm volatile("s_waitcnt vmcnt(0)" ::: "memory");
          __builtin_amdgcn_sched_barrier(0);
#pragma unroll
          for (int kk2 = 0; kk2 < 4; ++kk2)
#pragma unroll
            for (int mt = 0; mt < 4; ++mt) {
              acc[mt][0] = mfma16(a[kk2][mt], bg[0][hb * 4 + kk2], acc[mt][0]);
              acc[mt][1] = mfma16(a[kk2][mt], bg[1][hb * 4 + kk2], acc[mt][1]);
            }
        }
      }
#pragma unroll
      for (int mt = 0; mt < 4; ++mt)
#pragma unroll
        for (int nt = 0; nt < 2; ++nt)
#pragma unroll
          for (int r = 0; r < 4; ++r)
            red[w][mt * 16 + q * 4 + r][nt * 16 + s] = acc[mt][nt][r];
    }
    __syncthreads();
    if (tid < 128) {  // r-gate -> RH, one contiguous coherent 16B store
      int row = tid & 63, kg = tid >> 6;
      short8 o;
#pragma unroll
      for (int j = 0; j < 8; ++j) {
        int col = 16 + kg * 8 + j;
        float sum = red[0][row][col] + red[1][row][col] + red[2][row][col] + red[3][row][col];
        sum += LAYER ? bg1p[g * 32 + col] : xg[j];
        float gate = 1.f / (1.f + __expf(-sum));
        o[j] = (short)f2b(gate * hf[row][kg * 8 + j]);
      }
      stg_coh(&myRH[((size_t)(2 * g + kg) * 64 + row) * 8], o);
    } else {          // u-gate -> LDS (WG-local)
      int t2 = tid - 128;
      int row = t2 & 63, kg = t2 >> 6;
#pragma unroll
      for (int j = 0; j < 8; ++j) {
        int col = kg * 8 + j;
        float sum = red[0][row][col] + red[1][row][col] + red[2][row][col] + red[3][row][col];
        sum += LAYER ? bg1p[g * 32 + col] : xg[j];
        u_lds[row][col] = 1.f / (1.f + __expf(-sum));
      }
    }
    asm volatile("s_waitcnt vmcnt(0)" ::: "memory");
    if (l == 0 && w < 2) {   // early per-half stamp (before barrier)
#pragma unroll
      for (int r4 = 0; r4 < 4; ++r4) st_stamp(&SR[r4 * 64 + 2 * g + w], t);
    }
    __syncthreads();

    // ============ phase B: cell + state update ============
    {
      f32x4 acc[4] = {};
      if constexpr (LAYER == 0) {
        wait_sub<1, 16>(SR + repw, 16 * w, t);
        short8 a[4][4];
#pragma unroll
        for (int kk2 = 0; kk2 < 4; ++kk2) {
          int kl = w * 4 + kk2;
#pragma unroll
          for (int mt = 0; mt < 4; ++mt)
            a[kk2][mt] = ldg_coh(&myRH[(((size_t)(kl * 4 + q)) * 64 + mt * 16 + s) * 8]);
        }
        asm volatile("s_waitcnt vmcnt(0)" ::: "memory");
        __builtin_amdgcn_sched_barrier(0);
#pragma unroll
        for (int kk2 = 0; kk2 < 4; ++kk2)
#pragma unroll
          for (int mt = 0; mt < 4; ++mt)
            acc[mt] = mfma16(a[kk2][mt], bc[kk2], acc[mt]);
      } else {
        // w0,1: h0-part, already gated by phase A's SH0 wait -> no wait.
        // w2,3: rh1-part, wait only the 32 words of their half.
        if (w >= 2) wait_sub<1, 32>(SR + repw, 32 * (w & 1), t);
        const unsigned short* ab = (w >= 2) ? myRH : A0;
#pragma unroll
        for (int hb = 0; hb < 2; ++hb) {
          short8 a[4][4];
#pragma unroll
          for (int kk2 = 0; kk2 < 4; ++kk2) {
            int kl = ((w & 1) * 8 + hb * 4 + kk2);
#pragma unroll
            for (int mt = 0; mt < 4; ++mt)
              a[kk2][mt] = ldg_coh(&ab[(((size_t)(kl * 4 + q)) * 64 + mt * 16 + s) * 8]);
          }
          asm volatile("s_waitcnt vmcnt(0)" ::: "memory");
          __builtin_amdgcn_sched_barrier(0);
#pragma unroll
          for (int kk2 = 0; kk2 < 4; ++kk2)
#pragma unroll
            for (int mt = 0; mt < 4; ++mt)
              acc[mt] = mfma16(a[kk2][mt], bc[hb * 4 + kk2], acc[mt]);
        }
      }
#pragma unroll
      for (int mt = 0; mt < 4; ++mt)
#pragma unroll
        for (int r = 0; r < 4; ++r)
          red[w][mt * 16 + q * 4 + r][s] = acc[mt][r];
    }
    __syncthreads();
    if (tid < 128) {
      int row = tid & 63, kg = tid >> 6;
      short8 o;
#pragma unroll
      for (int j = 0; j < 8; ++j) {
        int cl = kg * 8 + j;
        float sum = red[0][row][cl] + red[1][row][cl] + red[2][row][cl] + red[3][row][cl];
        sum += LAYER ? bc1[16 * g + cl] : xc[j];
        float cv = tanhf(sum);
        float u = u_lds[row][cl];
        float hp = hf[row][cl];
        float hn = hp + u * (cv - hp);
        hf[row][cl] = hn;
        o[j] = (short)f2b(hn);
      }
      size_t ko = ((size_t)(2 * g + kg) * 64 + row) * 8;
      if (LAYER == 0) stg_coh(&H0ALL[(size_t)t * 32768 + ko], o);
      else            stg_coh(&H1ALL[(size_t)t * 32768 + ko], o);
    }
    asm volatile("s_waitcnt vmcnt(0)" ::: "memory");
    if (l == 0 && w < 2) {   // early per-half stamp (before barrier)
#pragma unroll
      for (int r4 = 0; r4 < 4; ++r4) st_stamp(&mySH[r4 * 64 + 2 * g + w], t);
      if (LAYER) {
#pragma unroll
        for (int r8 = 0; r8 < 8; ++r8) st_stamp(&SHW[r8 * 64 + 2 * g + w], t);
      }
    }
    __syncthreads();
  }

  // ---- final hidden (f32); hf stable after the loop's final __syncthreads ----
  {
    int col = tid & 15;
#pragma unroll
    for (int rr = 0; rr < 4; ++rr) {
      int row = (tid >> 4) * 4 + rr;
      hidden_out[(size_t)LAYER * 32768 + (size_t)row * 512 + 16 * g + col] = hf[row][col];
    }
  }
}

// ------------- worker path: logits tiles, nb-major (L2-resident B-block) ----
__device__ void worker_path(int wid, const unsigned short* __restrict__ A,
                            const unsigned short* __restrict__ Bf,
                            const float* __restrict__ bias, float* __restrict__ C,
                            const int* __restrict__ stamps, char* smem) {
  unsigned short* ldsA = (unsigned short*)smem;
  unsigned short* ldsB = (unsigned short*)(smem + 16384);
  const int* rep = stamps + (16 + (wid & 7)) * 64;
  int l = threadIdx.x & 63, w = threadIdx.x >> 6;
  int mh = w >> 1, nh = w & 1;
  int nb = wid % 80;
  int helper = wid / 80;                  // 0,1 for all nb; 2 exists for nb<32
  int nhelp = (nb < 32) ? 3 : 2;
  for (int tp = helper; tp < 64; tp += nhelp) {
    wait_sub<16, 64>(rep, 0, 2 * tp + 1);
    f32x4 acc[4][4] = {};
    for (int ko = 0; ko < 8; ++ko) {
      __syncthreads();
      for (int j = 0; j < 4; ++j) {
        int c = w * 4 + j;
        int m8 = c >> 1, ks = c & 1;
        int t = tp * 2 + (m8 >> 2);
        int kt = ko * 8 + ks * 4 + (l >> 4);
        int row = (m8 & 3) * 16 + (l & 15);
        size_t gidx = (((size_t)t * 64 + kt) * 64 + row) * 8;
        *reinterpret_cast<short8*>(&ldsA[(size_t)c * 512 + l * 8]) =
            *reinterpret_cast<const short8*>(&A[gidx]);
        size_t gb = (((size_t)(nb * 8 + (c >> 1)) * 16) + (size_t)(ko * 2 + (c & 1))) * 512 + (size_t)l * 8;
        *reinterpret_cast<short8*>(&ldsB[(size_t)c * 512 + l * 8]) =
            *reinterpret_cast<const short8*>(&Bf[gb]);
      }
      __syncthreads();
      for (int ks = 0; ks < 2; ++ks) {
        short8 a[4], b[4];
        for (int mt = 0; mt < 4; ++mt)
          a[mt] = *reinterpret_cast<const short8*>(&ldsA[((size_t)((mh * 4 + mt) * 2 + ks) * 64 + l) * 8]);
        for (int nt = 0; nt < 4; ++nt)
          b[nt] = *reinterpret_cast<const short8*>(&ldsB[((size_t)((nh * 4 + nt) * 2 + ks) * 64 + l) * 8]);
        for (int mt = 0; mt < 4; ++mt)
          for (int nt = 0; nt < 4; ++nt)
            acc[mt][nt] = mfma16(a[mt], b[nt], acc[mt][nt]);
      }
    }
    for (int mt = 0; mt < 4; ++mt) {
      for (int nt = 0; nt < 4; ++nt) {
        int col = nb * 128 + nh * 64 + nt * 16 + (l & 15);
        if (col >= NVOCAB) continue;
        float bv = bias[col];
        int row0 = tp * 128 + mh * 64 + mt * 16 + ((l >> 4) << 2);
        for (int r = 0; r < 4; ++r)
          C[(size_t)(row0 + r) * NVOCAB + col] = acc[mt][nt][r] + bv;
      }
    }
  }
}

__launch_bounds__(256, 1)
__global__ void fused_persist(const unsigned short* __restrict__ Wg0h, const unsigned short* __restrict__ Wc0h,
                              const unsigned short* __restrict__ Wg1, const unsigned short* __restrict__ Wc1,
                              const float* __restrict__ Xg0p, const float* __restrict__ Xc0p,
                              const float* __restrict__ bg1p, const float* __restrict__ bc1,
                              const float* __restrict__ hidden,
                              unsigned short* __restrict__ H0ALL, unsigned short* __restrict__ H1ALL,
                              const unsigned short* __restrict__ H0INITB, const unsigned short* __restrict__ H1INITB,
                              unsigned short* __restrict__ RH0, unsigned short* __restrict__ RH1,
                              int* __restrict__ stamps, float* __restrict__ hidden_out,
                              const unsigned short* __restrict__ Wout_f, const float* __restrict__ bout,
                              float* __restrict__ out) {
  __shared__ __align__(16) char smem[42496];
  int wg = blockIdx.x;
  if (wg >= NREC) {
    worker_path(wg - NREC, H1ALL, Wout_f, bout, out, stamps, smem);
    return;
  }
  float (*red)[64][33] = (float(*)[64][33])smem;
  float (*u_lds)[17] = (float(*)[17])(smem + 33792);
  float (*hf)[17] = (float(*)[17])(smem + 38144);
  int g = wg & 31;
  if (wg < 32)
    rec_layer<16, 0>(g, Wg0h, Wc0h, Xg0p, Xc0p, bg1p, bc1, hidden, H0ALL, H1ALL,
                     H0INITB, H1INITB, RH0, RH1, stamps, hidden_out,
                     *(float(*)[4][64][33])red, *(float(*)[64][17])u_lds, *(float(*)[64][17])hf);
  else
    rec_layer<32, 1>(g, Wg1, Wc1, Xg0p, Xc0p, bg1p, bc1, hidden, H0ALL, H1ALL,
                     H0INITB, H1INITB, RH0, RH1, stamps, hidden_out,
                     *(float(*)[4][64][33])red, *(float(*)[64][17])u_lds, *(float(*)[64][17])hf);
}

static inline int gridFor(long long n) { return (int)((n + 255) / 256); }

extern "C" void kernel_launch(void* const* d_in, const int* in_sizes, int n_in,
                              void* d_out, int out_size, void* d_ws, size_t ws_size,
                              hipStream_t stream) {
  const int*   inputs = (const int*)d_in[0];
  const float* hidden = (const float*)d_in[1];
  const float* embtab = (const float*)d_in[2];
  const float* Wg0 = (const float*)d_in[3];
  const float* bg0 = (const float*)d_in[4];
  const float* Wc0 = (const float*)d_in[5];
  const float* bc0 = (const float*)d_in[6];
  const float* Wg1 = (const float*)d_in[7];
  const float* bg1 = (const float*)d_in[8];
  const float* Wc1 = (const float*)d_in[9];
  const float* bc1 = (const float*)d_in[10];
  const float* Wout = (const float*)d_in[11];
  const float* bout = (const float*)d_in[12];
  float* out = (float*)d_out;

  // ---- workspace carve ----
  char* p = (char*)d_ws;
  size_t off = 0;
  auto carve = [&](size_t bytes) { char* r = p + off; off += (bytes + 255) & ~(size_t)255; return (void*)r; };
  unsigned short* XA     = (unsigned short*)carve((size_t)8192 * 512 * 2);
  unsigned short* Wg0x_f = (unsigned short*)carve((size_t)512 * 1024 * 2);
  unsigned short* Wg0h_f = (unsigned short*)carve((size_t)512 * 1024 * 2);
  unsigned short* Wc0x_f = (unsigned short*)carve((size_t)512 * 512 * 2);
  unsigned short* Wc0h_f = (unsigned short*)carve((size_t)512 * 512 * 2);
  unsigned short* Wg1_f  = (unsigned short*)carve((size_t)1024 * 1024 * 2);
  unsigned short* Wc1_f  = (unsigned short*)carve((size_t)1024 * 512 * 2);
  unsigned short* Wout_f = (unsigned short*)carve((size_t)512 * 10240 * 2);
  float* Xg0p = (float*)carve((size_t)8192 * 1024 * 4);
  float* Xc0p = (float*)carve((size_t)8192 * 512 * 4);
  unsigned short* H1ALL  = (unsigned short*)carve((size_t)128 * 32768 * 2);
  unsigned short* H0ALL  = (unsigned short*)carve((size_t)128 * 32768 * 2);
  unsigned short* H0INITB= (unsigned short*)carve((size_t)32768 * 2);
  unsigned short* H1INITB= (unsigned short*)carve((size_t)32768 * 2);
  unsigned short* RH0 = (unsigned short*)carve((size_t)32768 * 2);
  unsigned short* RH1 = (unsigned short*)carve((size_t)32768 * 2);
  float* bg0p = (float*)carve(1024 * 4);
  float* bg1p = (float*)carve(1024 * 4);
  int* stamps = (int*)carve(24 * 64 * 4);
  if (off > ws_size) return;

  // ---- pack weights into fragment-linear bf16 ----
  pack_frag<<<gridFor(64LL * 16 * 64), 256, 0, stream>>>(Wg0, Wg0x_f, 16, 0,   1024, 64, 1, 1024);
  pack_frag<<<gridFor(64LL * 16 * 64), 256, 0, stream>>>(Wg0, Wg0h_f, 16, 512, 1024, 64, 1, 1024);
  pack_frag<<<gridFor(32LL * 16 * 64), 256, 0, stream>>>(Wc0, Wc0x_f, 16, 0,   512,  32, 0, 512);
  pack_frag<<<gridFor(32LL * 16 * 64), 256, 0, stream>>>(Wc0, Wc0h_f, 16, 512, 512,  32, 0, 512);
  pack_frag<<<gridFor(64LL * 32 * 64), 256, 0, stream>>>(Wg1, Wg1_f,  32, 0,   1024, 64, 1, 1024);
  pack_frag<<<gridFor(32LL * 32 * 64), 256, 0, stream>>>(Wc1, Wc1_f,  32, 0,   512,  32, 0, 512);
  pack_frag<<<gridFor(640LL * 16 * 64), 256, 0, stream>>>(Wout, Wout_f, 16, 0, 10000, 640, 0, 10000);
  pack_bias<<<4, 256, 0, stream>>>(bg0, bg1, bg0p, bg1p);

  // ---- embedding + state/stamp init ----
  embed_gather<<<gridFor((long long)SEQ * 64 * 64), 256, 0, stream>>>(inputs, embtab, XA);
  init_states<<<gridFor(32768), 256, 0, stream>>>(hidden, H0INITB, H1INITB, stamps);

  // ---- precompute x-parts of layer-0 gates/cell ----
  gemm128<<<dim3(8, 64), 256, 0, stream>>>(XA, Wg0x_f, bg0p, Xg0p, 1024, 1024);
  gemm128<<<dim3(4, 64), 256, 0, stream>>>(XA, Wc0x_f, bc0, Xc0p, 512, 512);

  // ---- fused persistent: 64 recurrence WGs + 192 logits workers ----
  fused_persist<<<NTOT, 256, 0, stream>>>(Wg0h_f, Wc0h_f, Wg1_f, Wc1_f, Xg0p, Xc0p,
                                          bg1p, bc1, hidden, H0ALL, H1ALL,
                                          H0INITB, H1INITB, RH0, RH1,
                                          stamps, out + (size_t)81920000,
                                          Wout_f, bout, out);
}

// Round 15
// 1156.462 us; speedup vs baseline: 58.4687x; 1.1079x over previous
//
#include <hip/hip_runtime.h>
#include <cstdint>
#include <cstddef>

#define SEQ 128
#define BATCH 64
#define NVOCAB 10000
#define NREC 64
#define NWORK 192
#define NTOT 256

typedef __attribute__((ext_vector_type(8))) short short8;
typedef __attribute__((ext_vector_type(4))) float f32x4;

__device__ __forceinline__ unsigned short f2b(float f) {
  union { float f; unsigned u; } c; c.f = f;
  unsigned u = c.u;
  unsigned r = (u + 0x7fffu + ((u >> 16) & 1u)) >> 16;
  return (unsigned short)r;
}

__device__ __forceinline__ f32x4 mfma16(short8 a, short8 b, f32x4 c) {
  return __builtin_amdgcn_mfma_f32_16x16x32_bf16(a, b, c, 0, 0, 0);
}

// Coherent (cross-XCD) ops: bypass L1+L2, served at the coherence point.
__device__ __forceinline__ short8 ldg_coh(const unsigned short* p) {
  short8 r;
  asm volatile("global_load_dwordx4 %0, %1, off sc0 sc1" : "=v"(r) : "v"(p));
  return r;
}
__device__ __forceinline__ void stg_coh(unsigned short* p, short8 v) {
  asm volatile("global_store_dwordx4 %0, %1, off sc0 sc1" :: "v"(p), "v"(v) : "memory");
}
__device__ __forceinline__ void st_stamp(int* p, int v) {
  asm volatile("global_store_dword %0, %1, off sc0 sc1" :: "v"(p), "v"(v) : "memory");
}
__device__ __forceinline__ int ld_stamp(const int* p) {
  int r;
  asm volatile("global_load_dword %0, %1, off sc0 sc1" : "=v"(r) : "v"(p));
  return r;
}

// Wait until all 32 words of one stamp replica line are >= need. Per-wave.
template<int SLP>
__device__ __forceinline__ void wait_all32(const int* rep, int need) {
  if (need < 0) return;
  int idx = threadIdx.x & 31;
  int guard = 0;
  for (;;) {
    int v = ld_stamp(rep + idx);
    asm volatile("s_waitcnt vmcnt(0)" ::: "memory");
    if (__all(v >= need)) return;
    __builtin_amdgcn_s_sleep(SLP);
    if (++guard > 3000000) return;  // bail to wrong-output, never hang
  }
}

// Wait on a NW-word subset [base, base+NW) of a replica line (NW power of 2).
// Only the producers this wave actually consumes -- finer pacing, less traffic.
template<int SLP, int NW>
__device__ __forceinline__ void wait_sub(const int* rep, int base, int need) {
  if (need < 0) return;
  int idx = base + (threadIdx.x & (NW - 1));
  int guard = 0;
  for (;;) {
    int v = ld_stamp(rep + idx);
    asm volatile("s_waitcnt vmcnt(0)" ::: "memory");
    if (__all(v >= need)) return;
    __builtin_amdgcn_s_sleep(SLP);
    if (++guard > 3000000) return;
  }
}

// ---------------- packing: src f32 (K x N row-major) -> frag-linear bf16 ----
__global__ void pack_frag(const float* __restrict__ src, unsigned short* __restrict__ dst,
                          int ksteps, int row_off, int src_ld, int ntiles, int mode, int nreal) {
  int tid = blockIdx.x * 256 + threadIdx.x;
  int total = ntiles * ksteps * 64;
  if (tid >= total) return;
  int l = tid & 63;
  int ks = (tid >> 6) % ksteps;
  int nt = tid / (64 * ksteps);
  int n = nt * 16 + (l & 15);
  int col;
  bool valid = true;
  if (mode == 1) {
    int jc = n >> 5, s = n & 31;
    col = (s < 16) ? (16 * jc + s) : (512 + 16 * jc + (s - 16));
  } else {
    col = n;
    valid = (n < nreal);
  }
  int k0 = row_off + ks * 32 + ((l >> 4) << 3);
  short8 o;
  for (int j = 0; j < 8; ++j) {
    float x = valid ? src[(size_t)(k0 + j) * src_ld + col] : 0.f;
    o[j] = (short)f2b(x);
  }
  *reinterpret_cast<short8*>(&dst[(size_t)tid * 8]) = o;
}

__global__ void pack_bias(const float* __restrict__ bg0, const float* __restrict__ bg1,
                          float* __restrict__ bg0p, float* __restrict__ bg1p) {
  int p = blockIdx.x * 256 + threadIdx.x;
  if (p >= 1024) return;
  int jc = p >> 5, s = p & 31;
  int col = (s < 16) ? (16 * jc + s) : (512 + 16 * jc + (s - 16));
  bg0p[p] = bg0[col];
  bg1p[p] = bg1[col];
}

// ------------- embedding gather into kmat layout [t][ktile][row][8] bf16 ----
__global__ void embed_gather(const int* __restrict__ inp, const float* __restrict__ tab,
                             unsigned short* __restrict__ XA) {
  int tid = blockIdx.x * 256 + threadIdx.x;
  if (tid >= SEQ * 64 * 64) return;
  int row = tid & 63;
  int kt = (tid >> 6) & 63;
  int t = tid >> 12;
  int v = inp[t * BATCH + row];
  const float* s = &tab[(size_t)v * 512 + kt * 8];
  const float scale = 22.627416997969522f; // sqrt(512)
  short8 o;
  for (int j = 0; j < 8; ++j) o[j] = (short)f2b(s[j] * scale);
  *reinterpret_cast<short8*>(&XA[(size_t)tid * 8]) = o;
}

// ------------- init: h0/h1 initial bf16 kmat buffers, stamps=-1 ----
__global__ void init_states(const float* __restrict__ hid, unsigned short* __restrict__ H0INITB,
                            unsigned short* __restrict__ H1INITB, int* __restrict__ stamps) {
  int idx = blockIdx.x * 256 + threadIdx.x;
  if (idx < 24 * 64) stamps[idx] = -1;
  if (idx >= 64 * 512) return;
  int row = idx >> 9, c = idx & 511;
  size_t ko = (((size_t)(c >> 3)) * 64 + row) * 8 + (c & 7);
  H0INITB[ko] = f2b(hid[idx]);
  H1INITB[ko] = f2b(hid[64 * 512 + idx]);
}

// ------------- generic 128x128 LDS-tiled bf16 GEMM, K=512 (prologue only) ----
__launch_bounds__(256, 2)
__global__ void gemm128(const unsigned short* __restrict__ A, const unsigned short* __restrict__ Bf,
                        const float* __restrict__ bias, float* __restrict__ C,
                        int Nld, int Nreal) {
  __shared__ __align__(16) unsigned short ldsA[16 * 512];
  __shared__ __align__(16) unsigned short ldsB[16 * 512];
  int nb = blockIdx.x, yb = blockIdx.y;
  int l = threadIdx.x & 63, w = threadIdx.x >> 6;
  int mh = w >> 1, nh = w & 1;
  f32x4 acc[4][4] = {};
  for (int ko = 0; ko < 8; ++ko) {
    __syncthreads();
    for (int j = 0; j < 4; ++j) {
      int c = w * 4 + j;
      int m8 = c >> 1, ks = c & 1;
      int t = yb * 2 + (m8 >> 2);
      int kt = ko * 8 + ks * 4 + (l >> 4);
      int row = (m8 & 3) * 16 + (l & 15);
      size_t gidx = (((size_t)t * 64 + kt) * 64 + row) * 8;
      *reinterpret_cast<short8*>(&ldsA[(size_t)c * 512 + l * 8]) =
          *reinterpret_cast<const short8*>(&A[gidx]);
      size_t gb = (((size_t)(nb * 8 + (c >> 1)) * 16) + (size_t)(ko * 2 + (c & 1))) * 512 + (size_t)l * 8;
      *reinterpret_cast<short8*>(&ldsB[(size_t)c * 512 + l * 8]) =
          *reinterpret_cast<const short8*>(&Bf[gb]);
    }
    __syncthreads();
    for (int ks = 0; ks < 2; ++ks) {
      short8 a[4], b[4];
      for (int mt = 0; mt < 4; ++mt) {
        int m8 = mh * 4 + mt;
        a[mt] = *reinterpret_cast<const short8*>(&ldsA[((size_t)(m8 * 2 + ks) * 64 + l) * 8]);
      }
      for (int nt = 0; nt < 4; ++nt) {
        int n8 = nh * 4 + nt;
        b[nt] = *reinterpret_cast<const short8*>(&ldsB[((size_t)(n8 * 2 + ks) * 64 + l) * 8]);
      }
      for (int mt = 0; mt < 4; ++mt)
        for (int nt = 0; nt < 4; ++nt)
          acc[mt][nt] = mfma16(a[mt], b[nt], acc[mt][nt]);
    }
  }
  for (int mt = 0; mt < 4; ++mt) {
    for (int nt = 0; nt < 4; ++nt) {
      int col = nb * 128 + nh * 64 + nt * 16 + (l & 15);
      if (col >= Nreal) continue;
      float bv = bias[col];
      int row0 = yb * 128 + mh * 64 + mt * 16 + ((l >> 4) << 2);
      for (int r = 0; r < 4; ++r)
        C[(size_t)(row0 + r) * Nld + col] = acc[mt][nt][r] + bv;
    }
  }
}

// ------------- recurrence layer (stamp-synced, per-wave SUBSET waits) ----
// Stamp rows (64 ints each): 0-3 SR0, 4-7 SR1, 8-11 SH0, 12-15 SH1, 16-23 SHW.
// Each wave waits only on the stamps of the producers whose columns it reads:
// L0 wave w reads h/rh cols [128w,128w+127] -> producers 8w..8w+7 (8 words).
// L1 waves: w0/w1 h0-halves (16 words of SH0), w2/w3 h1|rh1-halves (16 words).
template<int KS, int LAYER>
__device__ void rec_layer(
    int g, const unsigned short* __restrict__ Wg, const unsigned short* __restrict__ Wc,
    const float* __restrict__ Xg0p, const float* __restrict__ Xc0p,
    const float* __restrict__ bg1p, const float* __restrict__ bc1,
    const float* __restrict__ hidden,
    unsigned short* __restrict__ H0ALL, unsigned short* __restrict__ H1ALL,
    const unsigned short* __restrict__ H0INITB, const unsigned short* __restrict__ H1INITB,
    unsigned short* __restrict__ RH0, unsigned short* __restrict__ RH1,
    int* __restrict__ stamps, float* __restrict__ hidden_out,
    float (&red)[4][64][33], float (&u_lds)[64][17], float (&hf)[64][17]) {
  constexpr int KQ = KS / 4;
  const int tid = threadIdx.x;
  const int l = tid & 63, w = tid >> 6;
  const int s = l & 15, q = l >> 4;

  int* SR   = stamps + (LAYER ? 4 : 0) * 64;
  int* SH0  = stamps + 8 * 64;
  int* SH1  = stamps + 12 * 64;
  int* SHW  = stamps + 16 * 64;
  int* mySH = LAYER ? SH1 : SH0;
  const int repw = ((g + w) & 3) * 64;
  unsigned short* myRH = LAYER ? RH1 : RH0;

  // ---- weights to registers (once, cached) ----
  short8 bg[2][KQ];
  short8 bc[KQ];
#pragma unroll
  for (int kk = 0; kk < KQ; ++kk) {
    int ks = w * KQ + kk;
    bg[0][kk] = *reinterpret_cast<const short8*>(&Wg[(((size_t)(2 * g) * KS + ks) * 64 + l) * 8]);
    bg[1][kk] = *reinterpret_cast<const short8*>(&Wg[(((size_t)(2 * g + 1) * KS + ks) * 64 + l) * 8]);
    bc[kk]    = *reinterpret_cast<const short8*>(&Wc[(((size_t)g * KS + ks) * 64 + l) * 8]);
  }

  // ---- init f32 h slice in LDS ----
  {
    int col = tid & 15;
#pragma unroll
    for (int rr = 0; rr < 4; ++rr) {
      int row = (tid >> 4) * 4 + rr;
      hf[row][col] = hidden[(size_t)LAYER * 32768 + (size_t)row * 512 + 16 * g + col];
    }
  }
  __syncthreads();

  for (int t = 0; t < 128; ++t) {
    // ---- L0: prefetch this step's X-part adds (no stamp dependency) ----
    float xg[8], xc[8];
    if constexpr (LAYER == 0) {
      int row = tid & 63;
      int kg = (tid >> 6) & 1;
      int base = (tid < 128) ? 16 : 0;
#pragma unroll
      for (int j = 0; j < 8; ++j)
        xg[j] = Xg0p[((size_t)(t * 64 + row)) * 1024 + g * 32 + base + kg * 8 + j];
#pragma unroll
      for (int j = 0; j < 8; ++j)
        xc[j] = Xc0p[((size_t)(t * 64 + row)) * 512 + 16 * g + kg * 8 + j];
    }

    const unsigned short* A0 = LAYER ? (H0ALL + (size_t)t * 32768)
                                     : (t ? (H0ALL + (size_t)(t - 1) * 32768) : H0INITB);
    const unsigned short* A1 = nullptr;
    if (LAYER) A1 = t ? (H1ALL + (size_t)(t - 1) * 32768) : H1INITB;

    // ============ phase A: gates ============
    {
      f32x4 acc[4][2] = {};
      if constexpr (LAYER == 0) {
        wait_sub<1, 8>(SH0 + repw, 8 * w, t - 1);
        short8 a[4][4];
#pragma unroll
        for (int kk2 = 0; kk2 < 4; ++kk2) {
          int kl = w * 4 + kk2;
#pragma unroll
          for (int mt = 0; mt < 4; ++mt)
            a[kk2][mt] = ldg_coh(&A0[(((size_t)(kl * 4 + q)) * 64 + mt * 16 + s) * 8]);
        }
        asm volatile("s_waitcnt vmcnt(0)" ::: "memory");
        __builtin_amdgcn_sched_barrier(0);
#pragma unroll
        for (int kk2 = 0; kk2 < 4; ++kk2)
#pragma unroll
          for (int mt = 0; mt < 4; ++mt) {
            acc[mt][0] = mfma16(a[kk2][mt], bg[0][kk2], acc[mt][0]);
            acc[mt][1] = mfma16(a[kk2][mt], bg[1][kk2], acc[mt][1]);
          }
      } else {
        // per-wave subset dependency wait
        if (w >= 2) wait_sub<1, 16>(SH1 + repw, 16 * (w & 1), t - 1);
        else        wait_sub<1, 16>(SH0 + repw, 16 * (w & 1), t);
        const unsigned short* ab = (w >= 2) ? A1 : A0;
#pragma unroll
        for (int hb = 0; hb < 2; ++hb) {
          short8 a[4][4];
#pragma unroll
          for (int kk2 = 0; kk2 < 4; ++kk2) {
            int kl = ((w & 1) * 8 + hb * 4 + kk2);  // w0/w2: kl 0-7, w1/w3: kl 8-15
#pragma unroll
            for (int mt = 0; mt < 4; ++mt)
              a[kk2][mt] = ldg_coh(&ab[(((size_t)(kl * 4 + q)) * 64 + mt * 16 + s) * 8]);
          }
          asm volatile("s_waitcnt vmcnt(0)" ::: "memory");
          __builtin_amdgcn_sched_barrier(0);
#pragma unroll
          for (int kk2 = 0; kk2 < 4; ++kk2)
#pragma unroll
            for (int mt = 0; mt < 4; ++mt) {
              acc[mt][0] = mfma16(a[kk2][mt], bg[0][hb * 4 + kk2], acc[mt][0]);
              acc[mt][1] = mfma16(a[kk2][mt], bg[1][hb * 4 + kk2], acc[mt][1]);
            }
        }
      }
#pragma unroll
      for (int mt = 0; mt < 4; ++mt)
#pragma unroll
        for (int nt = 0; nt < 2; ++nt)
#pragma unroll
          for (int r = 0; r < 4; ++r)
            red[w][mt * 16 + q * 4 + r][nt * 16 + s] = acc[mt][nt][r];
    }
    __syncthreads();
    if (tid < 128) {  // r-gate -> RH, one contiguous coherent 16B store
      int row = tid & 63, kg = tid >> 6;
      short8 o;
#pragma unroll
      for (int j = 0; j < 8; ++j) {
        int col = 16 + kg * 8 + j;
        float sum = red[0][row][col] + red[1][row][col] + red[2][row][col] + red[3][row][col];
        sum += LAYER ? bg1p[g * 32 + col] : xg[j];
        float gate = 1.f / (1.f + __expf(-sum));
        o[j] = (short)f2b(gate * hf[row][kg * 8 + j]);
      }
      stg_coh(&myRH[((size_t)(2 * g + kg) * 64 + row) * 8], o);
    } else {          // u-gate -> LDS (WG-local)
      int t2 = tid - 128;
      int row = t2 & 63, kg = t2 >> 6;
#pragma unroll
      for (int j = 0; j < 8; ++j) {
        int col = kg * 8 + j;
        float sum = red[0][row][col] + red[1][row][col] + red[2][row][col] + red[3][row][col];
        sum += LAYER ? bg1p[g * 32 + col] : xg[j];
        u_lds[row][col] = 1.f / (1.f + __expf(-sum));
      }
    }
    asm volatile("s_waitcnt vmcnt(0)" ::: "memory");
    __syncthreads();
    if (tid == 0) {
#pragma unroll
      for (int r = 0; r < 4; ++r) st_stamp(&SR[r * 64 + g], t);
    }

    // ============ phase B: cell + state update ============
    {
      f32x4 acc[4] = {};
      if constexpr (LAYER == 0) {
        wait_sub<1, 8>(SR + repw, 8 * w, t);
        short8 a[4][4];
#pragma unroll
        for (int kk2 = 0; kk2 < 4; ++kk2) {
          int kl = w * 4 + kk2;
#pragma unroll
          for (int mt = 0; mt < 4; ++mt)
            a[kk2][mt] = ldg_coh(&myRH[(((size_t)(kl * 4 + q)) * 64 + mt * 16 + s) * 8]);
        }
        asm volatile("s_waitcnt vmcnt(0)" ::: "memory");
        __builtin_amdgcn_sched_barrier(0);
#pragma unroll
        for (int kk2 = 0; kk2 < 4; ++kk2)
#pragma unroll
          for (int mt = 0; mt < 4; ++mt)
            acc[mt] = mfma16(a[kk2][mt], bc[kk2], acc[mt]);
      } else {
        // w0,1: h0-part, already gated by phase A's SH0 wait -> no wait.
        // w2,3: rh1-part, wait only the 16 producers of their half.
        if (w >= 2) wait_sub<1, 16>(SR + repw, 16 * (w & 1), t);
        const unsigned short* ab = (w >= 2) ? myRH : A0;
#pragma unroll
        for (int hb = 0; hb < 2; ++hb) {
          short8 a[4][4];
#pragma unroll
          for (int kk2 = 0; kk2 < 4; ++kk2) {
            int kl = ((w & 1) * 8 + hb * 4 + kk2);
#pragma unroll
            for (int mt = 0; mt < 4; ++mt)
              a[kk2][mt] = ldg_coh(&ab[(((size_t)(kl * 4 + q)) * 64 + mt * 16 + s) * 8]);
          }
          asm volatile("s_waitcnt vmcnt(0)" ::: "memory");
          __builtin_amdgcn_sched_barrier(0);
#pragma unroll
          for (int kk2 = 0; kk2 < 4; ++kk2)
#pragma unroll
            for (int mt = 0; mt < 4; ++mt)
              acc[mt] = mfma16(a[kk2][mt], bc[hb * 4 + kk2], acc[mt]);
        }
      }
#pragma unroll
      for (int mt = 0; mt < 4; ++mt)
#pragma unroll
        for (int r = 0; r < 4; ++r)
          red[w][mt * 16 + q * 4 + r][s] = acc[mt][r];
    }
    __syncthreads();
    if (tid < 128) {
      int row = tid & 63, kg = tid >> 6;
      short8 o;
#pragma unroll
      for (int j = 0; j < 8; ++j) {
        int cl = kg * 8 + j;
        float sum = red[0][row][cl] + red[1][row][cl] + red[2][row][cl] + red[3][row][cl];
        sum += LAYER ? bc1[16 * g + cl] : xc[j];
        float cv = tanhf(sum);
        float u = u_lds[row][cl];
        float hp = hf[row][cl];
        float hn = hp + u * (cv - hp);
        hf[row][cl] = hn;
        o[j] = (short)f2b(hn);
      }
      size_t ko = ((size_t)(2 * g + kg) * 64 + row) * 8;
      if (LAYER == 0) stg_coh(&H0ALL[(size_t)t * 32768 + ko], o);
      else            stg_coh(&H1ALL[(size_t)t * 32768 + ko], o);
    }
    asm volatile("s_waitcnt vmcnt(0)" ::: "memory");
    __syncthreads();
    if (tid == 0) {
#pragma unroll
      for (int r = 0; r < 4; ++r) st_stamp(&mySH[r * 64 + g], t);
      if (LAYER) {
#pragma unroll
        for (int r = 0; r < 8; ++r) st_stamp(&SHW[r * 64 + g], t);
      }
    }
  }

  // ---- final hidden (f32); hf stable after the last pre-stamp __syncthreads ----
  {
    int col = tid & 15;
#pragma unroll
    for (int rr = 0; rr < 4; ++rr) {
      int row = (tid >> 4) * 4 + rr;
      hidden_out[(size_t)LAYER * 32768 + (size_t)row * 512 + 16 * g + col] = hf[row][col];
    }
  }
}

// ------------- worker path: logits tiles, nb-major (L2-resident B-block) ----
// Worker keeps ONE 128-col Wout block across row-tiles -> its 131KB B-block
// stays hot in its XCD's L2 instead of re-fetching from LLC per row-tile.
// nb<32: 3 helpers (tp mod 3), nb>=32: 2 helpers (tp mod 2).
__device__ void worker_path(int wid, const unsigned short* __restrict__ A,
                            const unsigned short* __restrict__ Bf,
                            const float* __restrict__ bias, float* __restrict__ C,
                            const int* __restrict__ stamps, char* smem) {
  unsigned short* ldsA = (unsigned short*)smem;
  unsigned short* ldsB = (unsigned short*)(smem + 16384);
  const int* rep = stamps + (16 + (wid & 7)) * 64;
  int l = threadIdx.x & 63, w = threadIdx.x >> 6;
  int mh = w >> 1, nh = w & 1;
  int nb = wid % 80;
  int helper = wid / 80;                  // 0,1 for all nb; 2 exists for nb<32
  int nhelp = (nb < 32) ? 3 : 2;
  for (int tp = helper; tp < 64; tp += nhelp) {
    wait_all32<16>(rep, 2 * tp + 1);
    f32x4 acc[4][4] = {};
    for (int ko = 0; ko < 8; ++ko) {
      __syncthreads();
      for (int j = 0; j < 4; ++j) {
        int c = w * 4 + j;
        int m8 = c >> 1, ks = c & 1;
        int t = tp * 2 + (m8 >> 2);
        int kt = ko * 8 + ks * 4 + (l >> 4);
        int row = (m8 & 3) * 16 + (l & 15);
        size_t gidx = (((size_t)t * 64 + kt) * 64 + row) * 8;
        *reinterpret_cast<short8*>(&ldsA[(size_t)c * 512 + l * 8]) =
            *reinterpret_cast<const short8*>(&A[gidx]);
        size_t gb = (((size_t)(nb * 8 + (c >> 1)) * 16) + (size_t)(ko * 2 + (c & 1))) * 512 + (size_t)l * 8;
        *reinterpret_cast<short8*>(&ldsB[(size_t)c * 512 + l * 8]) =
            *reinterpret_cast<const short8*>(&Bf[gb]);
      }
      __syncthreads();
      for (int ks = 0; ks < 2; ++ks) {
        short8 a[4], b[4];
        for (int mt = 0; mt < 4; ++mt)
          a[mt] = *reinterpret_cast<const short8*>(&ldsA[((size_t)((mh * 4 + mt) * 2 + ks) * 64 + l) * 8]);
        for (int nt = 0; nt < 4; ++nt)
          b[nt] = *reinterpret_cast<const short8*>(&ldsB[((size_t)((nh * 4 + nt) * 2 + ks) * 64 + l) * 8]);
        for (int mt = 0; mt < 4; ++mt)
          for (int nt = 0; nt < 4; ++nt)
            acc[mt][nt] = mfma16(a[mt], b[nt], acc[mt][nt]);
      }
    }
    for (int mt = 0; mt < 4; ++mt) {
      for (int nt = 0; nt < 4; ++nt) {
        int col = nb * 128 + nh * 64 + nt * 16 + (l & 15);
        if (col >= NVOCAB) continue;
        float bv = bias[col];
        int row0 = tp * 128 + mh * 64 + mt * 16 + ((l >> 4) << 2);
        for (int r = 0; r < 4; ++r)
          C[(size_t)(row0 + r) * NVOCAB + col] = acc[mt][nt][r] + bv;
      }
    }
  }
}

__launch_bounds__(256, 1)
__global__ void fused_persist(const unsigned short* __restrict__ Wg0h, const unsigned short* __restrict__ Wc0h,
                              const unsigned short* __restrict__ Wg1, const unsigned short* __restrict__ Wc1,
                              const float* __restrict__ Xg0p, const float* __restrict__ Xc0p,
                              const float* __restrict__ bg1p, const float* __restrict__ bc1,
                              const float* __restrict__ hidden,
                              unsigned short* __restrict__ H0ALL, unsigned short* __restrict__ H1ALL,
                              const unsigned short* __restrict__ H0INITB, const unsigned short* __restrict__ H1INITB,
                              unsigned short* __restrict__ RH0, unsigned short* __restrict__ RH1,
                              int* __restrict__ stamps, float* __restrict__ hidden_out,
                              const unsigned short* __restrict__ Wout_f, const float* __restrict__ bout,
                              float* __restrict__ out) {
  __shared__ __align__(16) char smem[42496];
  int wg = blockIdx.x;
  if (wg >= NREC) {
    worker_path(wg - NREC, H1ALL, Wout_f, bout, out, stamps, smem);
    return;
  }
  float (*red)[64][33] = (float(*)[64][33])smem;
  float (*u_lds)[17] = (float(*)[17])(smem + 33792);
  float (*hf)[17] = (float(*)[17])(smem + 38144);
  int g = wg & 31;
  if (wg < 32)
    rec_layer<16, 0>(g, Wg0h, Wc0h, Xg0p, Xc0p, bg1p, bc1, hidden, H0ALL, H1ALL,
                     H0INITB, H1INITB, RH0, RH1, stamps, hidden_out,
                     *(float(*)[4][64][33])red, *(float(*)[64][17])u_lds, *(float(*)[64][17])hf);
  else
    rec_layer<32, 1>(g, Wg1, Wc1, Xg0p, Xc0p, bg1p, bc1, hidden, H0ALL, H1ALL,
                     H0INITB, H1INITB, RH0, RH1, stamps, hidden_out,
                     *(float(*)[4][64][33])red, *(float(*)[64][17])u_lds, *(float(*)[64][17])hf);
}

static inline int gridFor(long long n) { return (int)((n + 255) / 256); }

extern "C" void kernel_launch(void* const* d_in, const int* in_sizes, int n_in,
                              void* d_out, int out_size, void* d_ws, size_t ws_size,
                              hipStream_t stream) {
  const int*   inputs = (const int*)d_in[0];
  const float* hidden = (const float*)d_in[1];
  const float* embtab = (const float*)d_in[2];
  const float* Wg0 = (const float*)d_in[3];
  const float* bg0 = (const float*)d_in[4];
  const float* Wc0 = (const float*)d_in[5];
  const float* bc0 = (const float*)d_in[6];
  const float* Wg1 = (const float*)d_in[7];
  const float* bg1 = (const float*)d_in[8];
  const float* Wc1 = (const float*)d_in[9];
  const float* bc1 = (const float*)d_in[10];
  const float* Wout = (const float*)d_in[11];
  const float* bout = (const float*)d_in[12];
  float* out = (float*)d_out;

  // ---- workspace carve ----
  char* p = (char*)d_ws;
  size_t off = 0;
  auto carve = [&](size_t bytes) { char* r = p + off; off += (bytes + 255) & ~(size_t)255; return (void*)r; };
  unsigned short* XA     = (unsigned short*)carve((size_t)8192 * 512 * 2);
  unsigned short* Wg0x_f = (unsigned short*)carve((size_t)512 * 1024 * 2);
  unsigned short* Wg0h_f = (unsigned short*)carve((size_t)512 * 1024 * 2);
  unsigned short* Wc0x_f = (unsigned short*)carve((size_t)512 * 512 * 2);
  unsigned short* Wc0h_f = (unsigned short*)carve((size_t)512 * 512 * 2);
  unsigned short* Wg1_f  = (unsigned short*)carve((size_t)1024 * 1024 * 2);
  unsigned short* Wc1_f  = (unsigned short*)carve((size_t)1024 * 512 * 2);
  unsigned short* Wout_f = (unsigned short*)carve((size_t)512 * 10240 * 2);
  float* Xg0p = (float*)carve((size_t)8192 * 1024 * 4);
  float* Xc0p = (float*)carve((size_t)8192 * 512 * 4);
  unsigned short* H1ALL  = (unsigned short*)carve((size_t)128 * 32768 * 2);
  unsigned short* H0ALL  = (unsigned short*)carve((size_t)128 * 32768 * 2);
  unsigned short* H0INITB= (unsigned short*)carve((size_t)32768 * 2);
  unsigned short* H1INITB= (unsigned short*)carve((size_t)32768 * 2);
  unsigned short* RH0 = (unsigned short*)carve((size_t)32768 * 2);
  unsigned short* RH1 = (unsigned short*)carve((size_t)32768 * 2);
  float* bg0p = (float*)carve(1024 * 4);
  float* bg1p = (float*)carve(1024 * 4);
  int* stamps = (int*)carve(24 * 64 * 4);
  if (off > ws_size) return;

  // ---- pack weights into fragment-linear bf16 ----
  pack_frag<<<gridFor(64LL * 16 * 64), 256, 0, stream>>>(Wg0, Wg0x_f, 16, 0,   1024, 64, 1, 1024);
  pack_frag<<<gridFor(64LL * 16 * 64), 256, 0, stream>>>(Wg0, Wg0h_f, 16, 512, 1024, 64, 1, 1024);
  pack_frag<<<gridFor(32LL * 16 * 64), 256, 0, stream>>>(Wc0, Wc0x_f, 16, 0,   512,  32, 0, 512);
  pack_frag<<<gridFor(32LL * 16 * 64), 256, 0, stream>>>(Wc0, Wc0h_f, 16, 512, 512,  32, 0, 512);
  pack_frag<<<gridFor(64LL * 32 * 64), 256, 0, stream>>>(Wg1, Wg1_f,  32, 0,   1024, 64, 1, 1024);
  pack_frag<<<gridFor(32LL * 32 * 64), 256, 0, stream>>>(Wc1, Wc1_f,  32, 0,   512,  32, 0, 512);
  pack_frag<<<gridFor(640LL * 16 * 64), 256, 0, stream>>>(Wout, Wout_f, 16, 0, 10000, 640, 0, 10000);
  pack_bias<<<4, 256, 0, stream>>>(bg0, bg1, bg0p, bg1p);

  // ---- embedding + state/stamp init ----
  embed_gather<<<gridFor((long long)SEQ * 64 * 64), 256, 0, stream>>>(inputs, embtab, XA);
  init_states<<<gridFor(32768), 256, 0, stream>>>(hidden, H0INITB, H1INITB, stamps);

  // ---- precompute x-parts of layer-0 gates/cell ----
  gemm128<<<dim3(8, 64), 256, 0, stream>>>(XA, Wg0x_f, bg0p, Xg0p, 1024, 1024);
  gemm128<<<dim3(4, 64), 256, 0, stream>>>(XA, Wc0x_f, bc0, Xc0p, 512, 512);

  // ---- fused persistent: 64 recurrence WGs + 192 logits workers ----
  fused_persist<<<NTOT, 256, 0, stream>>>(Wg0h_f, Wc0h_f, Wg1_f, Wc1_f, Xg0p, Xc0p,
                                          bg1p, bc1, hidden, H0ALL, H1ALL,
                                          H0INITB, H1INITB, RH0, RH1,
                                          stamps, out + (size_t)81920000,
                                          Wout_f, bout, out);
}